// Round 11
// baseline (102660.693 us; speedup 1.0000x reference)
//
#include <hip/hip_runtime.h>
#include <stdint.h>

#define DEV static __device__ __forceinline__

namespace {
constexpr int Bq = 16, ENC = 512, DEC = 800, Dd = 256, Hh = 1024;
// ---- workspace float offsets ----
constexpr int WS_H   = 0;              // h [16][1024]
constexpr int WS_C   = WS_H  + 16384;  // c [1024][16]
constexpr int WS_CT  = WS_C  + 16384;  // ctx  [16][256]
constexpr int WS_NC  = WS_CT + 4096;   // nctx [16][256]
constexpr int WS_LOC = WS_NC + 4096;   // loc [2][16][8] (parity dbuf)
constexpr int WS_END = WS_LOC + 256;
constexpr size_t CTXOUT = (size_t)Bq*DEC*Dd;
}

DEV float frcp(float x){ return __builtin_amdgcn_rcpf(x); }
DEV float sigm(float x){ return frcp(1.0f + __expf(-x)); }
DEV float ftanh(float x){
  x = fminf(fmaxf(x, -15.0f), 15.0f);
  float e = __expf(2.0f*x);
  return (e - 1.0f) * frcp(e + 1.0f);
}
DEV float wred16(float v){
  v += __shfl_xor(v, 1); v += __shfl_xor(v, 2);
  v += __shfl_xor(v, 4); v += __shfl_xor(v, 8);
  return v;
}

// ---------------- init: h=0, c=0, ctx=0, nctx=enc[:,0,:], loc=-0.1 ----------------
extern "C" __global__ void gmm_init(const float* __restrict__ enc, float* __restrict__ wsf){
  int idx = blockIdx.x*blockDim.x + threadIdx.x;
  int n = gridDim.x*blockDim.x;
  for (int k = idx; k < 32768; k += n) wsf[WS_H + k] = 0.f;          // h, c
  for (int k = idx; k < 4096;  k += n) wsf[WS_CT + k] = 0.f;          // ctx
  for (int k = idx; k < 4096;  k += n){                               // nctx = enc[:,0,:]
    int b = k >> 8, d = k & 255;
    wsf[WS_NC + k] = enc[(size_t)b*ENC*Dd + d];
  }
  for (int k = idx; k < 256; k += n) wsf[WS_LOC + k] = -0.1f;         // loc both parities
}

// ---------------- KG(t): gates + LSTM cell -> h_t ----------------
// 256 blocks x 256 threads; block bk owns units bk*4..+4 (16 gate rows), all 16 batches.
extern "C" __global__ void __launch_bounds__(256) gmm_kg(
    const float* __restrict__ mel, const float* __restrict__ Wih,
    const float* __restrict__ Whh, const float* __restrict__ bih,
    const float* __restrict__ bhh, float* __restrict__ wsf, int t)
{
  const int bk = blockIdx.x, tid = threadIdx.x;
  const int b = tid >> 4, kl = tid & 15;

  __shared__ float g_lds[256];     // [row 16][b 16]

  const float* hb   = wsf + WS_H  + b*1024;
  const float* ctb  = wsf + WS_CT + b*256;
  const float* ncb  = wsf + WS_NC + b*256;
  const float* melb = mel + ((size_t)b*DEC + t)*Dd;

  float acc[16];
  #pragma unroll
  for (int r = 0; r < 16; ++r) acc[r] = 0.f;

  // k-outer, row-inner: x-chunk loaded once per chunk, reused across 16 rows.
  // row r -> gate=r>>2, unit=bk*4+(r&3); Wih row base offset = grow*768
  #pragma unroll 2
  for (int it = 0; it < 4; ++it){                 // mel part (q cols 0..255)
    int k = it*64 + kl*4;
    float4 xv = *reinterpret_cast<const float4*>(melb + k);
    #pragma unroll
    for (int r = 0; r < 16; ++r){
      size_t grow = (size_t)((r>>2)*1024 + bk*4 + (r&3));
      float4 wv = *reinterpret_cast<const float4*>(Wih + grow*768 + k);
      acc[r] = fmaf(wv.x,xv.x, fmaf(wv.y,xv.y, fmaf(wv.z,xv.z, fmaf(wv.w,xv.w, acc[r]))));
    }
  }
  #pragma unroll 2
  for (int it = 0; it < 4; ++it){                 // ctx part (cols 256..511)
    int k = it*64 + kl*4;
    float4 xv = *reinterpret_cast<const float4*>(ctb + k);
    #pragma unroll
    for (int r = 0; r < 16; ++r){
      size_t grow = (size_t)((r>>2)*1024 + bk*4 + (r&3));
      float4 wv = *reinterpret_cast<const float4*>(Wih + grow*768 + 256 + k);
      acc[r] = fmaf(wv.x,xv.x, fmaf(wv.y,xv.y, fmaf(wv.z,xv.z, fmaf(wv.w,xv.w, acc[r]))));
    }
  }
  #pragma unroll 2
  for (int it = 0; it < 4; ++it){                 // nctx part (cols 512..767)
    int k = it*64 + kl*4;
    float4 xv = *reinterpret_cast<const float4*>(ncb + k);
    #pragma unroll
    for (int r = 0; r < 16; ++r){
      size_t grow = (size_t)((r>>2)*1024 + bk*4 + (r&3));
      float4 wv = *reinterpret_cast<const float4*>(Wih + grow*768 + 512 + k);
      acc[r] = fmaf(wv.x,xv.x, fmaf(wv.y,xv.y, fmaf(wv.z,xv.z, fmaf(wv.w,xv.w, acc[r]))));
    }
  }
  #pragma unroll 4
  for (int it = 0; it < 16; ++it){                // Whh @ h
    int k = it*64 + kl*4;
    float4 xv = *reinterpret_cast<const float4*>(hb + k);
    #pragma unroll
    for (int r = 0; r < 16; ++r){
      size_t grow = (size_t)((r>>2)*1024 + bk*4 + (r&3));
      float4 wv = *reinterpret_cast<const float4*>(Whh + grow*1024 + k);
      acc[r] = fmaf(wv.x,xv.x, fmaf(wv.y,xv.y, fmaf(wv.z,xv.z, fmaf(wv.w,xv.w, acc[r]))));
    }
  }
  #pragma unroll
  for (int r = 0; r < 16; ++r){
    float v = wred16(acc[r]);
    if (kl == 0) g_lds[r*16 + b] = v;
  }
  __syncthreads();

  if (tid < 64){
    int u = tid >> 4, bb = tid & 15;
    int ug = bk*4 + u;
    float gi = g_lds[(0*4 + u)*16 + bb] + bih[ug]        + bhh[ug];
    float gf = g_lds[(1*4 + u)*16 + bb] + bih[1024 + ug] + bhh[1024 + ug];
    float gg = g_lds[(2*4 + u)*16 + bb] + bih[2048 + ug] + bhh[2048 + ug];
    float go = g_lds[(3*4 + u)*16 + bb] + bih[3072 + ug] + bhh[3072 + ug];
    float co = wsf[WS_C + ug*16 + bb];
    float c2 = sigm(gf)*co + sigm(gi)*ftanh(gg);
    float h2 = sigm(go)*ftanh(c2);
    wsf[WS_C + ug*16 + bb]   = c2;
    wsf[WS_H + bb*1024 + ug] = h2;
  }
}

// ---------------- KB(t): x1 + head (replicated) + align + ctx slice ----------------
// 256 blocks x 256 threads; block = (b = blk>>4, ds = blk&15). All 16 ds-blocks of a
// batch replicate x1/x2/out/softmax/align bitwise-identically; each computes its own
// 16-dim ctx/nctx slice. ds==0 writes align output + loc (parity dbuf).
extern "C" __global__ void __launch_bounds__(256) gmm_kb(
    const float* __restrict__ enc, const int* __restrict__ outlen,
    const int* __restrict__ condlen, const float* __restrict__ W1,
    const float* __restrict__ b1v, const float* __restrict__ W2,
    const float* __restrict__ Wlin, const float* __restrict__ blin,
    float* __restrict__ out, float* __restrict__ wsf, int t)
{
  const int b = blockIdx.x >> 4, ds = blockIdx.x & 15;
  const int tid = threadIdx.x;
  const int kl = tid & 15, rg = tid >> 4;

  __shared__ float x1l[256], x2l[256], outl[24];
  __shared__ float mixw[8], mixlc[8], mixis[8];
  __shared__ float albl[512];
  __shared__ float cpn[2][16][16];

  const float* hb = wsf + WS_H + b*1024;

  // x1 = leaky(W1 @ h[b] + b1): rows r = rg*16 + j
  {
    float a[16];
    #pragma unroll
    for (int j = 0; j < 16; ++j) a[j] = 0.f;
    #pragma unroll 4
    for (int it = 0; it < 16; ++it){
      int k = it*64 + kl*4;
      float4 xv = *reinterpret_cast<const float4*>(hb + k);
      #pragma unroll
      for (int j = 0; j < 16; ++j){
        float4 wv = *reinterpret_cast<const float4*>(W1 + (size_t)(rg*16 + j)*1024 + k);
        a[j] = fmaf(wv.x,xv.x, fmaf(wv.y,xv.y, fmaf(wv.z,xv.z, fmaf(wv.w,xv.w, a[j]))));
      }
    }
    #pragma unroll
    for (int j = 0; j < 16; ++j){
      float v = wred16(a[j]);
      if (kl == 0){
        int r = rg*16 + j;
        v += b1v[r];
        x1l[r] = (v >= 0.f) ? v : 0.1f*v;
      }
    }
  }
  __syncthreads();

  // x2 = tanh(W2 @ x1)
  {
    float a[16];
    #pragma unroll
    for (int j = 0; j < 16; ++j) a[j] = 0.f;
    #pragma unroll
    for (int it = 0; it < 4; ++it){
      int k = it*64 + kl*4;
      float4 xv = *reinterpret_cast<const float4*>(x1l + k);
      #pragma unroll
      for (int j = 0; j < 16; ++j){
        float4 wv = *reinterpret_cast<const float4*>(W2 + (size_t)(rg*16 + j)*256 + k);
        a[j] = fmaf(wv.x,xv.x, fmaf(wv.y,xv.y, fmaf(wv.z,xv.z, fmaf(wv.w,xv.w, a[j]))));
      }
    }
    #pragma unroll
    for (int j = 0; j < 16; ++j){
      float v = wred16(a[j]);
      if (kl == 0) x2l[rg*16 + j] = ftanh(v);
    }
  }
  __syncthreads();

  // out = blin + Wlin @ x2 (24 rows)
  if (tid < 24){
    float s = blin[tid];
    const float* wr = Wlin + (size_t)tid*256;
    #pragma unroll 8
    for (int k = 0; k < 256; ++k) s = fmaf(x2l[k], wr[k], s);
    outl[tid] = s;
  }
  __syncthreads();

  const int cond = condlen[b], olen = outlen[b];

  // softmax + loc/std (8 lanes, replicated deterministically in every ds block)
  if (tid < 8){
    float w = outl[tid];
    float mx = w;
    mx = fmaxf(mx, __shfl_xor(mx, 1)); mx = fmaxf(mx, __shfl_xor(mx, 2)); mx = fmaxf(mx, __shfl_xor(mx, 4));
    float e = __expf(w - mx);
    float sum = e;
    sum += __shfl_xor(sum, 1); sum += __shfl_xor(sum, 2); sum += __shfl_xor(sum, 4);
    mixw[tid] = e * frcp(sum);
    float cm1 = (float)cond - 1.0f;
    float dl = sigm(outl[8 + tid]) + 0.005f;
    float lcold = wsf[WS_LOC + (t & 1)*128 + b*8 + tid];
    float lc = lcold + dl;
    mixlc[tid] = lc;                          // align uses pre-clamp loc
    mixis[tid] = 1.0f + __expf(-outl[16 + tid]);
    if (ds == 0) wsf[WS_LOC + ((t + 1) & 1)*128 + b*8 + tid] = fminf(lc, cm1);
  }
  __syncthreads();

  // align (512 positions over 256 threads)
  #pragma unroll
  for (int e0 = 0; e0 < 2; ++e0){
    int e = tid + e0*256;
    float ef = (float)e;
    float a = 0.f;
    #pragma unroll
    for (int m = 0; m < 8; ++m){
      float df = mixlc[m] - ef;
      a += (ftanh((df + 0.5f)*mixis[m]) - ftanh((df - 0.5f)*mixis[m])) * mixw[m];
    }
    a *= 0.5f;
    bool valid = (e < cond) && (t < olen);
    if (!valid) a = 0.f;
    albl[e] = a;
    if (ds == 0)
      out[CTXOUT + (size_t)b*((size_t)DEC*ENC) + (size_t)t*ENC + e] = a;
  }
  __syncthreads();

  // ctx/nctx slice d = ds*16 + dl
  {
    int dl = tid & 15, eg = tid >> 4;
    int d0 = ds*16;
    const float* encb = enc + (size_t)b*ENC*Dd;
    float ca = 0.f, na = 0.f;
    #pragma unroll 4
    for (int i = 0; i < 32; ++i){
      int e = eg*32 + i;
      float av = albl[e];
      float nv = albl[(e + 511) & 511];      // next_w[e] = align[e-1 mod 512]
      float ev = encb[(size_t)e*256 + d0 + dl];
      ca = fmaf(av, ev, ca);
      na = fmaf(nv, ev, na);
    }
    cpn[0][eg][dl] = ca;
    cpn[1][eg][dl] = na;
  }
  __syncthreads();
  if (tid < 32){
    int z = tid >> 4, dd = tid & 15;
    float sum = 0.f;
    #pragma unroll
    for (int g = 0; g < 16; ++g) sum += cpn[z][g][dd];
    int d = ds*16 + dd;
    if (z == 0){
      wsf[WS_CT + b*256 + d] = sum;
      out[(size_t)b*((size_t)DEC*Dd) + (size_t)t*Dd + d] = sum;  // align pre-masked
    } else {
      wsf[WS_NC + b*256 + d] = sum;
    }
  }
}

extern "C" void kernel_launch(void* const* d_in, const int* in_sizes, int n_in,
                              void* d_out, int out_size, void* d_ws, size_t ws_size,
                              hipStream_t stream)
{
  const float* enc    = (const float*)d_in[0];
  const float* mel    = (const float*)d_in[1];
  const int*   outlen = (const int*)d_in[3];
  const int*   cond   = (const int*)d_in[4];
  const float* Wih    = (const float*)d_in[5];
  const float* Whh    = (const float*)d_in[6];
  const float* bih    = (const float*)d_in[7];
  const float* bhh    = (const float*)d_in[8];
  const float* W1     = (const float*)d_in[9];
  const float* b1v    = (const float*)d_in[10];
  const float* W2     = (const float*)d_in[11];
  const float* Wlin   = (const float*)d_in[12];
  const float* blin   = (const float*)d_in[13];
  float* outp = (float*)d_out;
  float* wsf  = (float*)d_ws;

  hipLaunchKernelGGL(gmm_init, dim3(64), dim3(256), 0, stream, enc, wsf);

  for (int t = 0; t < DEC; ++t){
    hipLaunchKernelGGL(gmm_kg, dim3(256), dim3(256), 0, stream,
                       mel, Wih, Whh, bih, bhh, wsf, t);
    hipLaunchKernelGGL(gmm_kb, dim3(256), dim3(256), 0, stream,
                       enc, outlen, cond, W1, b1v, W2, Wlin, blin, outp, wsf, t);
  }
}

// Round 12
// 60043.561 us; speedup vs baseline: 1.7098x; 1.7098x over previous
//
#include <hip/hip_runtime.h>
#include <stdint.h>

#define DEV static __device__ __forceinline__

namespace {
constexpr int Bx = 16, ENCx = 512, DECx = 800, Dx = 256, Hx = 1024;
constexpr int NBLK = 256, NTHR = 512;
constexpr int NCHAIN = 32;                      // 2 chain blocks per batch

// ---- workspace float offsets ----
constexpr int WS_H    = 0;                      // 2 x [16][1024]  (parity dbuf)
constexpr int WS_X1M  = WS_H + 2*Bx*Hx;         // 2 x [16][256]
constexpr int WS_CTX  = WS_X1M + 2*Bx*Dx;       // 2 x ([16][256] ctx | [16][256] nctx)
constexpr int WS_FEND = WS_CTX + 2*2*Bx*Dx;
// ---- int offsets (relative to wsf + WS_FEND), counters strided by 16 ----
constexpr int IW_HC  = 0;                       // hCnt[801]  (count to 256)
constexpr int IW_XC  = IW_HC + 801*16;          // x1Cnt[800] (count to 256)
constexpr int IW_CC  = IW_XC + 800*16;          // ctxCnt[800] (count to 32)
constexpr int IW_END = IW_CC + 800*16;
constexpr size_t CTXOUT = (size_t)Bx*DECx*Dx;

// ---- dynamic LDS float offsets ----
constexpr int LH_STR = 1028;                    // padded h stride
constexpr int CT_STR = 260;                     // padded ctx stride (region2 reuse of lh)
constexpr int LW_H   = 0;                       // 16*1028
constexpr int LW_WHH = LW_H + 16*LH_STR;        // 16*1024
constexpr int LDS_DYN_F = LW_WHH + 16384;       // 32832 floats
constexpr size_t SMEM_BYTES = (size_t)LDS_DYN_F * 4;   // 131328 B
}

DEV float frcp(float x){ return __builtin_amdgcn_rcpf(x); }
DEV float sigm(float x){ return frcp(1.0f + __expf(-x)); }
DEV float ftanh(float x){
  x = fminf(fmaxf(x, -15.0f), 15.0f);
  float e = __expf(2.0f*x);
  return (e - 1.0f) * frcp(e + 1.0f);
}
DEV float wred16(float v){
  v += __shfl_xor(v, 1); v += __shfl_xor(v, 2);
  v += __shfl_xor(v, 4); v += __shfl_xor(v, 8);
  return v;
}
DEV int   ld_rlx(const int* p){ return __hip_atomic_load(p, __ATOMIC_RELAXED, __HIP_MEMORY_SCOPE_AGENT); }
DEV float ldf_c(const float* p){ return __hip_atomic_load(p, __ATOMIC_RELAXED, __HIP_MEMORY_SCOPE_AGENT); }
DEV void  stf_c(float* p, float v){ __hip_atomic_store(p, v, __ATOMIC_RELAXED, __HIP_MEMORY_SCOPE_AGENT); }
DEV void  add_cnt(int* p){ __hip_atomic_fetch_add(p, 1, __ATOMIC_RELAXED, __HIP_MEMORY_SCOPE_AGENT); }
DEV void cbar(){ asm volatile("" ::: "memory"); }

DEV void spin_fma(){
  float x = 1.0f;
  #pragma unroll
  for (int i = 0; i < 16; ++i) x = fmaf(x, 1.0000001f, 1e-9f);
  asm volatile("" :: "v"(x));
}

// sc1 bulk loads: issue + wait inside one asm block
DEV void ld8_wait(float4 (&r)[8], const float* p){
  const float *a1=p+2048,*a2=p+4096,*a3=p+6144,*a4=p+8192,*a5=p+10240,*a6=p+12288,*a7=p+14336;
  asm volatile(
    "global_load_dwordx4 %0, %8, off sc1\n\t"
    "global_load_dwordx4 %1, %9, off sc1\n\t"
    "global_load_dwordx4 %2, %10, off sc1\n\t"
    "global_load_dwordx4 %3, %11, off sc1\n\t"
    "global_load_dwordx4 %4, %12, off sc1\n\t"
    "global_load_dwordx4 %5, %13, off sc1\n\t"
    "global_load_dwordx4 %6, %14, off sc1\n\t"
    "global_load_dwordx4 %7, %15, off sc1\n\t"
    "s_waitcnt vmcnt(0)"
    : "=&v"(r[0]),"=&v"(r[1]),"=&v"(r[2]),"=&v"(r[3]),
      "=&v"(r[4]),"=&v"(r[5]),"=&v"(r[6]),"=&v"(r[7])
    : "v"(p),"v"(a1),"v"(a2),"v"(a3),"v"(a4),"v"(a5),"v"(a6),"v"(a7)
    : "memory");
}
DEV void ld4_wait(float4 (&r)[4], const float* p){
  const float *a1=p+2048,*a2=p+4096,*a3=p+6144;
  asm volatile(
    "global_load_dwordx4 %0, %4, off sc1\n\t"
    "global_load_dwordx4 %1, %5, off sc1\n\t"
    "global_load_dwordx4 %2, %6, off sc1\n\t"
    "global_load_dwordx4 %3, %7, off sc1\n\t"
    "s_waitcnt vmcnt(0)"
    : "=&v"(r[0]),"=&v"(r[1]),"=&v"(r[2]),"=&v"(r[3])
    : "v"(p),"v"(a1),"v"(a2),"v"(a3)
    : "memory");
}

// all-wave wait on a global counter: wave0 polls, stamps LDS; others spin on LDS
DEV void wait_cnt(int* p, int target, volatile int* lslot, int stamp){
  const int tid = threadIdx.x;
  if (tid < 64){
    while (ld_rlx(p) < target) spin_fma();
    if (tid == 0) *lslot = stamp;
  } else {
    while (*lslot < stamp) spin_fma();
  }
  __syncthreads();
  cbar();
}

DEV void gchunk(float (&acc)[2][4], float4 wa, float4 wb, const float* xlane, size_t xstride, int b4){
  #pragma unroll
  for (int bi = 0; bi < 4; ++bi){
    float4 xv = *reinterpret_cast<const float4*>(xlane + (size_t)(b4*4 + bi)*xstride);
    acc[0][bi] = fmaf(wa.x,xv.x, fmaf(wa.y,xv.y, fmaf(wa.z,xv.z, fmaf(wa.w,xv.w, acc[0][bi]))));
    acc[1][bi] = fmaf(wb.x,xv.x, fmaf(wb.y,xv.y, fmaf(wb.z,xv.z, fmaf(wb.w,xv.w, acc[1][bi]))));
  }
}

extern "C" __global__ void gmm_init(float* wsf){
  int* wsi = (int*)(wsf + WS_FEND);
  int idx = blockIdx.x*blockDim.x + threadIdx.x;
  for (int k = idx; k < IW_END; k += gridDim.x*blockDim.x) wsi[k] = 0;
}

extern "C" __global__ void __launch_bounds__(NTHR, 1) gmm_main(
    const float* __restrict__ enc, const float* __restrict__ mel,
    const int* __restrict__ outlen, const int* __restrict__ condlen,
    const float* __restrict__ Wih, const float* __restrict__ Whh,
    const float* __restrict__ bih, const float* __restrict__ bhh,
    const float* __restrict__ W1,  const float* __restrict__ b1v,
    const float* __restrict__ W2,  const float* __restrict__ Wlin,
    const float* __restrict__ blin,
    float* __restrict__ out, float* __restrict__ wsf)
{
  const int bk = blockIdx.x, tid = threadIdx.x;
  const int lane = tid & 63;
  const int klane4 = (tid & 15) * 4;
  const int b4 = (tid >> 4) & 3;
  const int wid = tid >> 6;

  int* wsi  = (int*)(wsf + WS_FEND);
  int* hCnt = wsi + IW_HC;     // stride 16
  int* xCnt = wsi + IW_XC;
  int* cCnt = wsi + IW_CC;
  float* hm   = wsf + WS_H;
  float* x1m  = wsf + WS_X1M;
  float* ctxm = wsf + WS_CTX;

  extern __shared__ float lds[];
  float* lh   = lds + LW_H;
  float* lwhh = lds + LW_WHH;

  __shared__ float g_lds[256];
  __shared__ float bsum[16];
  __shared__ float cl[64];
  __shared__ float x1l[256];
  __shared__ float x2p[512];
  __shared__ float x2l[256];
  __shared__ float outp[384];
  __shared__ float outl[24];
  __shared__ float mixw[8], mixlc[8], mixis[8];
  __shared__ float locl[8];
  __shared__ float albl[512];
  __shared__ float cpn[2][4][128];
  __shared__ int   s_cond, s_olen;
  __shared__ int   lfh, lfx, lfc;

  if (tid == 0){ lfh = 0; lfx = 0; lfc = 0; }

  const int jidx0 = 2*wid;
  const int j0 = (jidx0 >> 2)*1024 + bk*4 + (jidx0 & 3);
  const int j1 = ((jidx0+1) >> 2)*1024 + bk*4 + ((jidx0+1) & 3);
  const float* WihR0 = Wih + (size_t)j0*768;   // read-only -> L2-resident
  const float* WihR1 = Wih + (size_t)j1*768;

  const bool is_chain = (bk < NCHAIN);
  const int  cb  = bk >> 1;        // chain batch
  const int  hf2 = bk & 1;         // chain half (d range hf2*128..+128)

  // ---------------- one-time staging ----------------
  #pragma unroll
  for (int jj = jidx0; jj <= jidx0 + 1; ++jj){
    const int gj = (jj >> 2)*1024 + bk*4 + (jj & 3);
    float4* dst = (float4*)(lwhh + jj*1024);
    const float4* s = (const float4*)(Whh + (size_t)gj*1024);
    for (int i = lane; i < 256; i += 64) dst[i] = s[i];
  }
  if (tid < 16){
    int g = tid >> 2, ul = tid & 3, u = bk*4 + ul;
    bsum[tid] = bih[g*1024 + u] + bhh[g*1024 + u];
  }
  float4 w2r[32];
  if (is_chain){
    if (tid == 0){ s_cond = condlen[cb]; s_olen = outlen[cb]; }
    if (tid < 8) locl[tid] = -0.1f;
    int r = tid >> 1, hf = tid & 1;
    const float* w2row = W2 + (size_t)r*256 + hf*128;
    #pragma unroll
    for (int i = 0; i < 32; ++i) w2r[i] = *reinterpret_cast<const float4*>(w2row + i*4);
  }
  __syncthreads();

  // stage h master (parity) -> LDS
  auto write_h = [&](int t){
    float4 r[8];
    ld8_wait(r, hm + (t & 1)*(Bx*Hx) + tid*4);
    #pragma unroll
    for (int i = 0; i < 8; ++i){
      int rr = 2*i + (tid >> 8);
      *reinterpret_cast<float4*>(lh + rr*LH_STR + (tid & 255)*4) = r[i];
    }
    __syncthreads();
  };

  // ---------------- prologue: gates t=0 -> h_0 (q=[mel0, 0, enc[:,0,:]], h=0, c=0)
  {
    float acc[2][4] = {{0,0,0,0},{0,0,0,0}};
    #pragma unroll
    for (int it = 0; it < 4; ++it){
      int k = it*64 + klane4;
      gchunk(acc, *(const float4*)(WihR0 + k), *(const float4*)(WihR1 + k),
             mel + k, (size_t)DECx*Dx, b4);
    }
    #pragma unroll
    for (int it = 0; it < 4; ++it){
      int k = it*64 + klane4;
      gchunk(acc, *(const float4*)(WihR0 + 512 + k), *(const float4*)(WihR1 + 512 + k),
             enc + k, (size_t)ENCx*Dx, b4);
    }
    #pragma unroll
    for (int jj = 0; jj < 2; ++jj)
      #pragma unroll
      for (int bi = 0; bi < 4; ++bi){
        float v = wred16(acc[jj][bi]);
        if ((tid & 15) == 0) g_lds[(jidx0 + jj)*16 + b4*4 + bi] = v;
      }
    __syncthreads();
    if (tid < 64){
      int b = tid & 15, ul = tid >> 4, u = bk*4 + ul;
      float gi = g_lds[( 0 + ul)*16 + b] + bsum[ul];
      float gg = g_lds[( 8 + ul)*16 + b] + bsum[8 + ul];
      float go = g_lds[(12 + ul)*16 + b] + bsum[12 + ul];
      float c2 = sigm(gi) * ftanh(gg);
      float h2 = sigm(go) * ftanh(c2);
      cl[b*4 + ul] = c2;
      stf_c(hm + b*1024 + u, h2);           // parity 0 = h_0
    }
    __syncthreads();
    if (tid == 0) add_cnt(hCnt + 0*16);
  }

  // ---------------- main loop ----------------
  for (int t = 0; t < DECx; ++t){
    const int par = t & 1;
    const bool last = (t == DECx - 1);

    // ---- handoff 1: h_t ready -> stage + one x1 row for all batches
    wait_cnt(hCnt + t*16, NBLK, &lfh, t + 1);
    write_h(t);
    if (tid < 256){
      int b = tid >> 4, kl = tid & 15;
      const float* W1r = W1 + (size_t)bk*1024;
      float a = 0.f;
      #pragma unroll
      for (int it = 0; it < 16; ++it){
        int k = it*64 + kl*4;
        float4 wv = *reinterpret_cast<const float4*>(W1r + k);
        float4 xv = *reinterpret_cast<const float4*>(lh + (size_t)b*LH_STR + k);
        a = fmaf(wv.x,xv.x, fmaf(wv.y,xv.y, fmaf(wv.z,xv.z, fmaf(wv.w,xv.w, a))));
      }
      a = wred16(a);
      if (kl == 0){
        a += b1v[bk];
        a = (a >= 0.f) ? a : 0.1f*a;
        stf_c(x1m + par*(Bx*Dx) + b*256 + bk, a);
      }
    }
    __syncthreads();                         // vmcnt(0): x1 stores at coherence point
    if (tid == 0) add_cnt(xCnt + t*16);

    float acc[2][4] = {{0,0,0,0},{0,0,0,0}};

    if (is_chain){
      // ---- handoff 2: x1 ready -> full head chain + ctx half, block-local
      wait_cnt(xCnt + t*16, NBLK, &lfx, t + 1);
      if (tid < 256) x1l[tid] = ldf_c(x1m + par*(Bx*Dx) + cb*256 + tid);
      __syncthreads();
      {
        int hf = tid & 1;
        const float* x1b = x1l + hf*128;
        float a = 0.f;
        #pragma unroll
        for (int i = 0; i < 32; ++i){
          float4 xv = *(const float4*)(x1b + i*4);
          a = fmaf(w2r[i].x,xv.x, fmaf(w2r[i].y,xv.y, fmaf(w2r[i].z,xv.z, fmaf(w2r[i].w,xv.w, a))));
        }
        x2p[tid] = a;
      }
      __syncthreads();
      if (tid < 256) x2l[tid] = ftanh(x2p[2*tid] + x2p[2*tid + 1]);
      __syncthreads();
      if (tid < 384){
        int r = tid >> 4, ks = tid & 15;
        const float* wr = Wlin + (size_t)r*256 + ks*16;
        const float* xb = x2l + ks*16;
        float s = 0.f;
        #pragma unroll
        for (int k = 0; k < 16; ++k) s = fmaf(xb[k], wr[k], s);
        outp[tid] = s;
      }
      __syncthreads();
      if (tid < 24){
        float s = blin[tid];
        #pragma unroll
        for (int j = 0; j < 16; ++j) s += outp[tid*16 + j];
        outl[tid] = s;
      }
      __syncthreads();
      if (tid < 8){
        float w = outl[tid];
        float mx = w;
        mx = fmaxf(mx, __shfl_xor(mx, 1)); mx = fmaxf(mx, __shfl_xor(mx, 2)); mx = fmaxf(mx, __shfl_xor(mx, 4));
        float e = __expf(w - mx);
        float sum = e;
        sum += __shfl_xor(sum, 1); sum += __shfl_xor(sum, 2); sum += __shfl_xor(sum, 4);
        mixw[tid] = e * frcp(sum);
        float cm1 = (float)s_cond - 1.0f;
        float dl = sigm(outl[8 + tid]) + 0.005f;
        float lc = locl[tid] + dl;
        mixlc[tid] = lc;
        locl[tid]  = fminf(lc, cm1);
        mixis[tid] = 1.0f + __expf(-outl[16 + tid]);
      }
      __syncthreads();
      {
        int e = tid;
        float ef = (float)e;
        float a = 0.f;
        #pragma unroll
        for (int m = 0; m < 8; ++m){
          float df = mixlc[m] - ef;
          a += (ftanh((df + 0.5f)*mixis[m]) - ftanh((df - 0.5f)*mixis[m])) * mixw[m];
        }
        a *= 0.5f;
        bool valid = (e < s_cond) && (t < s_olen);
        if (!valid) a = 0.f;
        albl[e] = a;
        if (hf2 == 0)
          out[CTXOUT + (size_t)cb*((size_t)DECx*ENCx) + (size_t)t*ENCx + e] = a;
      }
      __syncthreads();
      {
        // ctx/nctx half: d = hf2*128 + dl
        int dl = tid & 127, eg = tid >> 7;     // 4 e-groups x 128 e
        const float* encb = enc + (size_t)cb*ENCx*Dx + hf2*128;
        float ca = 0.f, na = 0.f;
        #pragma unroll 4
        for (int i = 0; i < 128; ++i){
          int e = eg*128 + i;
          float av = albl[e];
          float nv = albl[(e + 511) & 511];
          float ev = encb[(size_t)e*256 + dl];
          ca = fmaf(av, ev, ca);
          na = fmaf(nv, ev, na);
        }
        cpn[0][eg][dl & 127] = 0.f;  // placeholder to keep shape; real store below
        // store partials: cpn[z][eg][dl]
        cpn[0][eg][dl] = ca;
        cpn[1][eg][dl] = na;
      }
      __syncthreads();
      if (tid < 256){
        int z = tid >> 7, dd = tid & 127;
        float s = cpn[z][0][dd] + cpn[z][1][dd] + cpn[z][2][dd] + cpn[z][3][dd];
        int d = hf2*128 + dd;
        stf_c(ctxm + par*(2*Bx*Dx) + z*(Bx*Dx) + cb*256 + d, s);
        if (z == 0)
          out[(size_t)cb*((size_t)DECx*Dx) + (size_t)t*Dx + d] = s;
      }
      __syncthreads();                       // vmcnt(0): ctx at coherence point
      if (tid == 0) add_cnt(cCnt + t*16);
      // gate partial AFTER the chain (lh still holds h_t)
      if (!last){
        const float* melt = mel + (size_t)(t + 1)*Dx;
        #pragma unroll
        for (int it = 0; it < 4; ++it){
          int k = it*64 + klane4;
          gchunk(acc, *(const float4*)(WihR0 + k), *(const float4*)(WihR1 + k),
                 melt + k, (size_t)DECx*Dx, b4);
        }
        #pragma unroll 4
        for (int it = 0; it < 16; ++it){
          int k = it*64 + klane4;
          gchunk(acc, *(const float4*)(lwhh + jidx0*1024 + k), *(const float4*)(lwhh + (jidx0+1)*1024 + k),
                 lh + k, LH_STR, b4);
        }
      }
    } else {
      // gate blocks: partial overlaps the chain phase
      if (!last){
        const float* melt = mel + (size_t)(t + 1)*Dx;
        #pragma unroll
        for (int it = 0; it < 4; ++it){
          int k = it*64 + klane4;
          gchunk(acc, *(const float4*)(WihR0 + k), *(const float4*)(WihR1 + k),
                 melt + k, (size_t)DECx*Dx, b4);
        }
        #pragma unroll 4
        for (int it = 0; it < 16; ++it){
          int k = it*64 + klane4;
          gchunk(acc, *(const float4*)(lwhh + jidx0*1024 + k), *(const float4*)(lwhh + (jidx0+1)*1024 + k),
                 lh + k, LH_STR, b4);
        }
      }
    }

    // ---- handoff 3: ctx ready -> region2 gate cols + cell -> h_{t+1}
    if (!last){
      wait_cnt(cCnt + t*16, NCHAIN, &lfc, t + 1);
      {
        float4 cr[4];
        ld4_wait(cr, ctxm + par*(2*Bx*Dx) + tid*4);   // 8192 floats: ctx | nctx
        #pragma unroll
        for (int i = 0; i < 4; ++i){
          int r = 8*i + (tid >> 6);
          *reinterpret_cast<float4*>(lh + r*CT_STR + (tid & 63)*4) = cr[i];
        }
      }
      __syncthreads();
      #pragma unroll
      for (int it = 0; it < 4; ++it){
        int k = it*64 + klane4;
        gchunk(acc, *(const float4*)(WihR0 + 256 + k), *(const float4*)(WihR1 + 256 + k),
               lh + k, CT_STR, b4);
      }
      #pragma unroll
      for (int it = 0; it < 4; ++it){
        int k = it*64 + klane4;
        gchunk(acc, *(const float4*)(WihR0 + 512 + k), *(const float4*)(WihR1 + 512 + k),
               lh + 16*CT_STR + k, CT_STR, b4);
      }
      #pragma unroll
      for (int jj = 0; jj < 2; ++jj)
        #pragma unroll
        for (int bi = 0; bi < 4; ++bi){
          float v = wred16(acc[jj][bi]);
          if ((tid & 15) == 0) g_lds[(jidx0 + jj)*16 + b4*4 + bi] = v;
        }
      __syncthreads();
      if (tid < 64){
        int b = tid & 15, ul = tid >> 4, u = bk*4 + ul;
        float gi = g_lds[( 0 + ul)*16 + b] + bsum[ul];
        float gf = g_lds[( 4 + ul)*16 + b] + bsum[4 + ul];
        float gg = g_lds[( 8 + ul)*16 + b] + bsum[8 + ul];
        float go = g_lds[(12 + ul)*16 + b] + bsum[12 + ul];
        float co = cl[b*4 + ul];
        float c2 = sigm(gf)*co + sigm(gi)*ftanh(gg);
        float h2 = sigm(go)*ftanh(c2);
        cl[b*4 + ul] = c2;
        stf_c(hm + ((t + 1) & 1)*(Bx*Hx) + b*1024 + u, h2);
      }
      __syncthreads();                       // vmcnt(0): h at coherence point
      if (tid == 0) add_cnt(hCnt + (t + 1)*16);
    }
  }
}

extern "C" void kernel_launch(void* const* d_in, const int* in_sizes, int n_in,
                              void* d_out, int out_size, void* d_ws, size_t ws_size,
                              hipStream_t stream)
{
  const float* enc    = (const float*)d_in[0];
  const float* mel    = (const float*)d_in[1];
  const int*   outlen = (const int*)d_in[3];
  const int*   cond   = (const int*)d_in[4];
  const float* Wih    = (const float*)d_in[5];
  const float* Whh    = (const float*)d_in[6];
  const float* bih    = (const float*)d_in[7];
  const float* bhh    = (const float*)d_in[8];
  const float* W1     = (const float*)d_in[9];
  const float* b1v    = (const float*)d_in[10];
  const float* W2     = (const float*)d_in[11];
  const float* Wlin   = (const float*)d_in[12];
  const float* blin   = (const float*)d_in[13];
  float* outp = (float*)d_out;
  float* wsf  = (float*)d_ws;

  (void)hipFuncSetAttribute((const void*)gmm_main,
                            hipFuncAttributeMaxDynamicSharedMemorySize,
                            (int)SMEM_BYTES);

  hipLaunchKernelGGL(gmm_init, dim3(64), dim3(256), 0, stream, wsf);

  void* args[] = {
    (void*)&enc, (void*)&mel, (void*)&outlen, (void*)&cond,
    (void*)&Wih, (void*)&Whh, (void*)&bih, (void*)&bhh,
    (void*)&W1, (void*)&b1v, (void*)&W2, (void*)&Wlin, (void*)&blin,
    (void*)&outp, (void*)&wsf
  };
  (void)hipLaunchCooperativeKernel((void*)gmm_main, dim3(NBLK), dim3(NTHR),
                                   args, SMEM_BYTES, stream);
}

// Round 13
// 50261.072 us; speedup vs baseline: 2.0425x; 1.1946x over previous
//
#include <hip/hip_runtime.h>
#include <stdint.h>

#define DEV static __device__ __forceinline__

namespace {
constexpr int Bx = 16, ENCx = 512, DECx = 800, Dx = 256, Hx = 1024;
constexpr int NGATE = 128, NCHAIN = 32, NBLK = NGATE + NCHAIN, NTHR = 512;

// ---- workspace float offsets ----
constexpr int WS_HBH  = 0;                 // 2 buf x 16384 ushort (bf16 h) = 16384 float-slots
constexpr int WS_CTXH = WS_HBH + 16384;    // 2 buf x 8192 ushort (bf16 ctx|nctx) = 8192
constexpr int WS_X1M  = WS_CTXH + 8192;    // 2 x [16][256] fp32
constexpr int WS_FEND = WS_X1M + 8192;
// ---- int offsets (relative to wsf + WS_FEND) ----
constexpr int IW_HSLOT = 0;                // 128 slots (monotone step stamps)
constexpr int IW_XSLOT = 128;              // 128 slots
constexpr int IW_CSLOT = 256;              // 32 slots (pad to 64)
constexpr int IW_HRDY  = 320;              // 8 replicas, stride 16
constexpr int IW_XRDY  = 448;
constexpr int IW_CRDY  = 576;
constexpr int IW_END   = 704;
constexpr size_t CTXOUT = (size_t)Bx*DECx*Dx;

// ---- dynamic LDS float offsets ----
constexpr int LH_STR = 1028;               // padded h stride (fp32)
constexpr int CT_STR = 260;                // padded ctx stride (region2 reuse of lh)
constexpr int LW_H   = 0;                  // 16*1028 fp32
constexpr int LW_WHH = LW_H + 16*LH_STR;   // 32 rows x 512 uints (bf16 Whh) = 16384 uints
constexpr int LDS_DYN_F = LW_WHH + 16384;  // 32832
constexpr size_t SMEM_BYTES = (size_t)LDS_DYN_F * 4;   // 131,328 B
}

DEV float frcp(float x){ return __builtin_amdgcn_rcpf(x); }
DEV float sigm(float x){ return frcp(1.0f + __expf(-x)); }
DEV float ftanh(float x){
  x = fminf(fmaxf(x, -15.0f), 15.0f);
  float e = __expf(2.0f*x);
  return (e - 1.0f) * frcp(e + 1.0f);
}
DEV float wred16(float v){
  v += __shfl_xor(v, 1); v += __shfl_xor(v, 2);
  v += __shfl_xor(v, 4); v += __shfl_xor(v, 8);
  return v;
}
DEV int   ld_rlx(const int* p){ return __hip_atomic_load(p, __ATOMIC_RELAXED, __HIP_MEMORY_SCOPE_AGENT); }
DEV void  st_rlx(int* p, int v){ __hip_atomic_store(p, v, __ATOMIC_RELAXED, __HIP_MEMORY_SCOPE_AGENT); }
DEV void  st_rlx_u32(unsigned* p, unsigned v){ __hip_atomic_store(p, v, __ATOMIC_RELAXED, __HIP_MEMORY_SCOPE_AGENT); }
DEV float ldf_c(const float* p){ return __hip_atomic_load(p, __ATOMIC_RELAXED, __HIP_MEMORY_SCOPE_AGENT); }
DEV void  stf_c(float* p, float v){ __hip_atomic_store(p, v, __ATOMIC_RELAXED, __HIP_MEMORY_SCOPE_AGENT); }
DEV void cbar(){ asm volatile("" ::: "memory"); }

// bf16 pack (round-nearest-even) / unpack (exact shift)
DEV unsigned pack_bf16(float lo, float hi){
  unsigned a = __builtin_bit_cast(unsigned, lo);
  unsigned b = __builtin_bit_cast(unsigned, hi);
  a += 0x7FFFu + ((a >> 16) & 1u);
  b += 0x7FFFu + ((b >> 16) & 1u);
  return (a >> 16) | (b & 0xFFFF0000u);
}
DEV float bflo(unsigned w){ return __builtin_bit_cast(float, w << 16); }
DEV float bfhi(unsigned w){ return __builtin_bit_cast(float, w & 0xFFFF0000u); }

// sc1 bulk loads: issue + wait inside one asm block
DEV void ld4_wait(float4 (&r)[4], const float* p){
  const float *a1=p+2048,*a2=p+4096,*a3=p+6144;
  asm volatile(
    "global_load_dwordx4 %0, %4, off sc1\n\t"
    "global_load_dwordx4 %1, %5, off sc1\n\t"
    "global_load_dwordx4 %2, %6, off sc1\n\t"
    "global_load_dwordx4 %3, %7, off sc1\n\t"
    "s_waitcnt vmcnt(0)"
    : "=&v"(r[0]),"=&v"(r[1]),"=&v"(r[2]),"=&v"(r[3])
    : "v"(p),"v"(a1),"v"(a2),"v"(a3)
    : "memory");
}
DEV void ld2_wait(float4 (&r)[2], const float* p){
  const float *a1=p+2048;
  asm volatile(
    "global_load_dwordx4 %0, %2, off sc1\n\t"
    "global_load_dwordx4 %1, %3, off sc1\n\t"
    "s_waitcnt vmcnt(0)"
    : "=&v"(r[0]),"=&v"(r[1])
    : "v"(p),"v"(a1)
    : "memory");
}
DEV int4 ld4i_sc1(const int* p){
  int4 r;
  asm volatile("global_load_dwordx4 %0, %1, off sc1\n\ts_waitcnt vmcnt(0)"
    : "=&v"(r) : "v"(p) : "memory");
  return r;
}

// waiter: wave0 polls its replica (s_sleep throttled), stamps LDS; other waves spin LDS
DEV void wait_rdy(int* rdy8, int repl, int target, volatile int* lslot){
  const int tid = threadIdx.x;
  if (tid < 64){
    while (ld_rlx(rdy8 + repl*16) < target) __builtin_amdgcn_s_sleep(8);
    if (tid == 0) *lslot = target;
  } else {
    while (*lslot < target) __builtin_amdgcn_s_sleep(1);
  }
  __syncthreads();
  cbar();
}

// detector: wave0 scans nq*4 slots with dwordx4, then publishes 8 replicas
DEV void detect_pub(int* slots, int nq, int* rdy8, int target, volatile int* lslot){
  const int tid = threadIdx.x;
  if (tid < 64){
    const int* my = slots + tid*4;
    const bool active = (tid < nq);
    for (;;){
      bool ok = true;
      if (active){
        int4 v = ld4i_sc1(my);
        ok = (v.x >= target) & (v.y >= target) & (v.z >= target) & (v.w >= target);
      }
      if (__ballot(ok) == ~0ull) break;
      __builtin_amdgcn_s_sleep(8);
    }
    if (tid < 8) st_rlx(rdy8 + tid*16, target);
    if (tid == 0) *lslot = target;
  } else {
    while (*lslot < target) __builtin_amdgcn_s_sleep(1);
  }
  __syncthreads();
  cbar();
}

extern "C" __global__ void gmm_init(float* wsf){
  int* wsi = (int*)(wsf + WS_FEND);
  int idx = blockIdx.x*blockDim.x + threadIdx.x;
  for (int k = idx; k < IW_END; k += gridDim.x*blockDim.x) wsi[k] = 0;
}

extern "C" __global__ void __launch_bounds__(NTHR, 1) gmm_main(
    const float* __restrict__ enc, const float* __restrict__ mel,
    const int* __restrict__ outlen, const int* __restrict__ condlen,
    const float* __restrict__ Wih, const float* __restrict__ Whh,
    const float* __restrict__ bih, const float* __restrict__ bhh,
    const float* __restrict__ W1,  const float* __restrict__ b1v,
    const float* __restrict__ W2,  const float* __restrict__ Wlin,
    const float* __restrict__ blin,
    float* __restrict__ out, float* __restrict__ wsf)
{
  const int bk = blockIdx.x, tid = threadIdx.x;
  const int klane4 = (tid & 15) * 4;
  const int b4 = (tid >> 4) & 3;
  const int wid = tid >> 6;

  int* wsi   = (int*)(wsf + WS_FEND);
  int* hslot = wsi + IW_HSLOT;
  int* xslot = wsi + IW_XSLOT;
  int* cslot = wsi + IW_CSLOT;
  int* hrdy  = wsi + IW_HRDY;
  int* xrdy  = wsi + IW_XRDY;
  int* crdy  = wsi + IW_CRDY;
  unsigned short* hbh = (unsigned short*)(wsf + WS_HBH);   // 2 x 16384 ushort
  unsigned* ctx32u    = (unsigned*)(wsf + WS_CTXH);        // 2 x 4096 uints
  float* x1m = wsf + WS_X1M;                               // 2 x 4096 fp32

  extern __shared__ float lds[];
  float*    lh      = lds + LW_H;
  unsigned* lwhh_u  = (unsigned*)(lds + LW_WHH);
  const uint2* lwhh2 = (const uint2*)(lds + LW_WHH);

  __shared__ float g_lds[512];
  __shared__ float bsum[32];
  __shared__ float cl[128];
  __shared__ float hstg[128];
  __shared__ float x1l[256];
  __shared__ float x2p[512];
  __shared__ float x2l[256];
  __shared__ float outp[384];
  __shared__ float outl[24];
  __shared__ float mixw[8], mixlc[8], mixis[8];
  __shared__ float locl[8];
  __shared__ float albl[512];
  __shared__ float cpn[2][4][128];
  __shared__ int   s_cond, s_olen;
  __shared__ int   lfh, lfx, lfc;

  if (tid == 0){ lfh = 0; lfx = 0; lfc = 0; }

  const bool is_gate = (bk < NGATE);
  const int  cid = bk - NGATE;
  const int  cb  = cid >> 1;
  const int  hf2 = cid & 1;
  const int  repl = bk & 7;

  // gate: local rows r (0..31): global gate row = (r>>3)*1024 + bk*8 + (r&7)
  const int r0 = wid*4;
  const float* wih[4];
  if (is_gate){
    #pragma unroll
    for (int r = 0; r < 4; ++r){
      int lr = r0 + r;
      wih[r] = Wih + (size_t)((lr>>3)*1024 + bk*8 + (lr&7))*768;
    }
  }

  // ---------------- one-time staging ----------------
  float4 w2r[32];
  if (is_gate){
    // Whh rows -> LDS bf16
    for (int i = tid; i < 16384; i += NTHR){
      int r = i >> 9, c = i & 511;
      size_t gr = (size_t)((r>>3)*1024 + bk*8 + (r&7));
      lwhh_u[i] = pack_bf16(Whh[gr*1024 + 2*c], Whh[gr*1024 + 2*c + 1]);
    }
    if (tid < 32){
      int g = tid >> 3, u = bk*8 + (tid & 7);
      bsum[tid] = bih[g*1024 + u] + bhh[g*1024 + u];
    }
  } else {
    if (tid == 0){ s_cond = condlen[cb]; s_olen = outlen[cb]; }
    if (tid < 8) locl[tid] = -0.1f;
    int r = tid >> 1, hf = tid & 1;
    const float* w2row = W2 + (size_t)r*256 + hf*128;
    #pragma unroll
    for (int i = 0; i < 32; ++i) w2r[i] = *reinterpret_cast<const float4*>(w2row + i*4);
  }
  __syncthreads();

  // stage bf16 h master -> LDS fp32 (32 KB sc1)
  auto write_h = [&](int t){
    float4 r[4];
    ld4_wait(r, (const float*)(hbh + (t & 1)*16384) + tid*4);
    #pragma unroll
    for (int i = 0; i < 4; ++i){
      unsigned wx = __builtin_bit_cast(unsigned, r[i].x);
      unsigned wy = __builtin_bit_cast(unsigned, r[i].y);
      unsigned wz = __builtin_bit_cast(unsigned, r[i].z);
      unsigned ww = __builtin_bit_cast(unsigned, r[i].w);
      int b = i*4 + (tid >> 7);
      float* d = lh + b*LH_STR + (tid & 127)*8;
      d[0] = bflo(wx); d[1] = bfhi(wx); d[2] = bflo(wy); d[3] = bfhi(wy);
      d[4] = bflo(wz); d[5] = bfhi(wz); d[6] = bflo(ww); d[7] = bfhi(ww);
    }
    __syncthreads();
  };

  // gate reduce + cell + bf16 h publish (writes buffer bsel, stamps hslot with stamp)
  auto cell_and_publish = [&](float (&acc)[4][4], int bsel, int stamp, bool first){
    #pragma unroll
    for (int r = 0; r < 4; ++r)
      #pragma unroll
      for (int bi = 0; bi < 4; ++bi){
        float v = wred16(acc[r][bi]);
        if ((tid & 15) == 0) g_lds[(r0 + r)*16 + b4*4 + bi] = v;
      }
    __syncthreads();
    if (tid < 128){
      int u = tid >> 4, b = tid & 15;
      float gi = g_lds[( 0 + u)*16 + b] + bsum[u];
      float gg = g_lds[(16 + u)*16 + b] + bsum[16 + u];
      float go = g_lds[(24 + u)*16 + b] + bsum[24 + u];
      float c2;
      if (first){
        c2 = sigm(gi) * ftanh(gg);
      } else {
        float gf = g_lds[(8 + u)*16 + b] + bsum[8 + u];
        c2 = sigm(gf)*cl[tid] + sigm(gi)*ftanh(gg);
      }
      float h2 = sigm(go)*ftanh(c2);
      cl[tid] = c2;
      hstg[u*16 + b] = h2;
    }
    __syncthreads();
    if (tid < 64){
      int p = tid >> 4, b = tid & 15;
      unsigned w = pack_bf16(hstg[(2*p)*16 + b], hstg[(2*p + 1)*16 + b]);
      st_rlx_u32((unsigned*)hbh + bsel*8192 + b*512 + bk*4 + p, w);
    }
    __syncthreads();                     // drain: h at coherence point
    if (tid == 0) st_rlx(hslot + bk, stamp);
  };

  // ---------------- prologue: gates t=0 (q=[mel0, 0, enc[:,0,:]], h=0, c=0) -> h_0
  if (is_gate){
    float acc[4][4] = {};
    #pragma unroll
    for (int it = 0; it < 4; ++it){
      int k = it*64 + klane4;
      float4 wv[4];
      #pragma unroll
      for (int r = 0; r < 4; ++r) wv[r] = *reinterpret_cast<const float4*>(wih[r] + k);
      #pragma unroll
      for (int bi = 0; bi < 4; ++bi){
        float4 xv = *reinterpret_cast<const float4*>(mel + (size_t)(b4*4 + bi)*DECx*Dx + k);
        #pragma unroll
        for (int r = 0; r < 4; ++r)
          acc[r][bi] = fmaf(wv[r].x,xv.x, fmaf(wv[r].y,xv.y, fmaf(wv[r].z,xv.z, fmaf(wv[r].w,xv.w, acc[r][bi]))));
      }
    }
    #pragma unroll
    for (int it = 0; it < 4; ++it){
      int k = it*64 + klane4;
      float4 wv[4];
      #pragma unroll
      for (int r = 0; r < 4; ++r) wv[r] = *reinterpret_cast<const float4*>(wih[r] + 512 + k);
      #pragma unroll
      for (int bi = 0; bi < 4; ++bi){
        float4 xv = *reinterpret_cast<const float4*>(enc + (size_t)(b4*4 + bi)*ENCx*Dx + k);
        #pragma unroll
        for (int r = 0; r < 4; ++r)
          acc[r][bi] = fmaf(wv[r].x,xv.x, fmaf(wv[r].y,xv.y, fmaf(wv[r].z,xv.z, fmaf(wv[r].w,xv.w, acc[r][bi]))));
      }
    }
    cell_and_publish(acc, 0, 1, true);
  }

  // ---------------- main loop ----------------
  for (int t = 0; t < DECx; ++t){
    const int par = t & 1;
    const bool last = (t == DECx - 1);

    if (is_gate){
      // ---- convoy 1: h_t ready
      if (bk == 0) detect_pub(hslot, 32, hrdy, t + 1, &lfh);
      else         wait_rdy(hrdy, repl, t + 1, &lfh);
      write_h(t);

      // ---- x1 rows 2bk, 2bk+1 (h local)
      {
        int row = tid >> 8;
        int b = (tid >> 4) & 15, kl = tid & 15;
        const float* W1r = W1 + (size_t)(2*bk + row)*1024;
        float a = 0.f;
        #pragma unroll
        for (int it = 0; it < 16; ++it){
          int k = it*64 + kl*4;
          float4 wv = *reinterpret_cast<const float4*>(W1r + k);
          float4 xv = *reinterpret_cast<const float4*>(lh + (size_t)b*LH_STR + k);
          a = fmaf(wv.x,xv.x, fmaf(wv.y,xv.y, fmaf(wv.z,xv.z, fmaf(wv.w,xv.w, a))));
        }
        a = wred16(a);
        if (kl == 0){
          a += b1v[2*bk + row];
          a = (a >= 0.f) ? a : 0.1f*a;
          stf_c(x1m + par*4096 + b*256 + 2*bk + row, a);
        }
      }
      __syncthreads();                   // drain: x1 at coherence point
      if (tid == 0) st_rlx(xslot + bk, t + 1);

      // ---- region 1 (overlaps chain): mel_{t+1} + Whh(bf16 LDS) @ h_t
      float acc[4][4] = {};
      if (!last){
        const int tt = t + 1;
        #pragma unroll
        for (int it = 0; it < 4; ++it){
          int k = it*64 + klane4;
          float4 wv[4];
          #pragma unroll
          for (int r = 0; r < 4; ++r) wv[r] = *reinterpret_cast<const float4*>(wih[r] + k);
          #pragma unroll
          for (int bi = 0; bi < 4; ++bi){
            float4 xv = *reinterpret_cast<const float4*>(mel + ((size_t)(b4*4 + bi)*DECx + tt)*Dx + k);
            #pragma unroll
            for (int r = 0; r < 4; ++r)
              acc[r][bi] = fmaf(wv[r].x,xv.x, fmaf(wv[r].y,xv.y, fmaf(wv[r].z,xv.z, fmaf(wv[r].w,xv.w, acc[r][bi]))));
          }
        }
        #pragma unroll 4
        for (int it = 0; it < 16; ++it){
          int k = it*64 + klane4;
          uint2 wv2[4];
          #pragma unroll
          for (int r = 0; r < 4; ++r) wv2[r] = lwhh2[(size_t)(r0 + r)*256 + it*16 + (tid & 15)];
          #pragma unroll
          for (int bi = 0; bi < 4; ++bi){
            float4 xv = *reinterpret_cast<const float4*>(lh + (size_t)(b4*4 + bi)*LH_STR + k);
            #pragma unroll
            for (int r = 0; r < 4; ++r){
              float w0 = bflo(wv2[r].x), w1 = bfhi(wv2[r].x);
              float w2 = bflo(wv2[r].y), w3 = bfhi(wv2[r].y);
              acc[r][bi] = fmaf(w0,xv.x, fmaf(w1,xv.y, fmaf(w2,xv.z, fmaf(w3,xv.w, acc[r][bi]))));
            }
          }
        }
      }

      if (!last){
        // ---- convoy 3: ctx_t ready
        if (bk == 0) detect_pub(cslot, 8, crdy, t + 1, &lfc);
        else         wait_rdy(crdy, repl, t + 1, &lfc);
        // stage bf16 ctx|nctx -> LDS fp32
        {
          float4 cr[2];
          ld2_wait(cr, (const float*)(ctx32u + par*4096) + tid*4);
          #pragma unroll
          for (int i = 0; i < 2; ++i){
            unsigned wx = __builtin_bit_cast(unsigned, cr[i].x);
            unsigned wy = __builtin_bit_cast(unsigned, cr[i].y);
            unsigned wz = __builtin_bit_cast(unsigned, cr[i].z);
            unsigned ww = __builtin_bit_cast(unsigned, cr[i].w);
            int base = i*2048 + tid*4;
            int z = base >> 11, b = (base >> 7) & 15, j = base & 127;
            float* d = lh + (z*16 + b)*CT_STR + 2*j;
            d[0] = bflo(wx); d[1] = bfhi(wx); d[2] = bflo(wy); d[3] = bfhi(wy);
            d[4] = bflo(wz); d[5] = bfhi(wz); d[6] = bflo(ww); d[7] = bfhi(ww);
          }
        }
        __syncthreads();
        // region 2: Wih cols 256..767 @ [ctx | nctx]
        #pragma unroll
        for (int it = 0; it < 4; ++it){
          int k = it*64 + klane4;
          float4 wv[4];
          #pragma unroll
          for (int r = 0; r < 4; ++r) wv[r] = *reinterpret_cast<const float4*>(wih[r] + 256 + k);
          #pragma unroll
          for (int bi = 0; bi < 4; ++bi){
            float4 xv = *reinterpret_cast<const float4*>(lh + (size_t)(b4*4 + bi)*CT_STR + k);
            #pragma unroll
            for (int r = 0; r < 4; ++r)
              acc[r][bi] = fmaf(wv[r].x,xv.x, fmaf(wv[r].y,xv.y, fmaf(wv[r].z,xv.z, fmaf(wv[r].w,xv.w, acc[r][bi]))));
          }
        }
        #pragma unroll
        for (int it = 0; it < 4; ++it){
          int k = it*64 + klane4;
          float4 wv[4];
          #pragma unroll
          for (int r = 0; r < 4; ++r) wv[r] = *reinterpret_cast<const float4*>(wih[r] + 512 + k);
          #pragma unroll
          for (int bi = 0; bi < 4; ++bi){
            float4 xv = *reinterpret_cast<const float4*>(lh + (size_t)(16 + b4*4 + bi)*CT_STR + k);
            #pragma unroll
            for (int r = 0; r < 4; ++r)
              acc[r][bi] = fmaf(wv[r].x,xv.x, fmaf(wv[r].y,xv.y, fmaf(wv[r].z,xv.z, fmaf(wv[r].w,xv.w, acc[r][bi]))));
          }
        }
        cell_and_publish(acc, (t + 1) & 1, t + 2, false);
      }
    } else {
      // ---------------- chain blocks ----------------
      // ---- convoy 2: x1 ready
      if (bk == NGATE) detect_pub(xslot, 32, xrdy, t + 1, &lfx);
      else             wait_rdy(xrdy, repl, t + 1, &lfx);
      if (tid < 256) x1l[tid] = ldf_c(x1m + par*4096 + cb*256 + tid);
      __syncthreads();
      {
        int hf = tid & 1;
        const float* x1b = x1l + hf*128;
        float a = 0.f;
        #pragma unroll
        for (int i = 0; i < 32; ++i){
          float4 xv = *(const float4*)(x1b + i*4);
          a = fmaf(w2r[i].x,xv.x, fmaf(w2r[i].y,xv.y, fmaf(w2r[i].z,xv.z, fmaf(w2r[i].w,xv.w, a))));
        }
        x2p[tid] = a;
      }
      __syncthreads();
      if (tid < 256) x2l[tid] = ftanh(x2p[2*tid] + x2p[2*tid + 1]);
      __syncthreads();
      if (tid < 384){
        int r = tid >> 4, ks = tid & 15;
        const float* wr = Wlin + (size_t)r*256 + ks*16;
        const float* xb = x2l + ks*16;
        float s = 0.f;
        #pragma unroll
        for (int k = 0; k < 16; ++k) s = fmaf(xb[k], wr[k], s);
        outp[tid] = s;
      }
      __syncthreads();
      if (tid < 24){
        float s = blin[tid];
        #pragma unroll
        for (int j = 0; j < 16; ++j) s += outp[tid*16 + j];
        outl[tid] = s;
      }
      __syncthreads();
      if (tid < 8){
        float w = outl[tid];
        float mx = w;
        mx = fmaxf(mx, __shfl_xor(mx, 1)); mx = fmaxf(mx, __shfl_xor(mx, 2)); mx = fmaxf(mx, __shfl_xor(mx, 4));
        float e = __expf(w - mx);
        float sum = e;
        sum += __shfl_xor(sum, 1); sum += __shfl_xor(sum, 2); sum += __shfl_xor(sum, 4);
        mixw[tid] = e * frcp(sum);
        float cm1 = (float)s_cond - 1.0f;
        float dl = sigm(outl[8 + tid]) + 0.005f;
        float lc = locl[tid] + dl;
        mixlc[tid] = lc;
        locl[tid]  = fminf(lc, cm1);
        mixis[tid] = 1.0f + __expf(-outl[16 + tid]);
      }
      __syncthreads();
      {
        float ef = (float)tid;
        float a = 0.f;
        #pragma unroll
        for (int m = 0; m < 8; ++m){
          float df = mixlc[m] - ef;
          a += (ftanh((df + 0.5f)*mixis[m]) - ftanh((df - 0.5f)*mixis[m])) * mixw[m];
        }
        a *= 0.5f;
        bool valid = (tid < s_cond) && (t < s_olen);
        if (!valid) a = 0.f;
        albl[tid] = a;
        if (hf2 == 0)
          out[CTXOUT + (size_t)cb*((size_t)DECx*ENCx) + (size_t)t*ENCx + tid] = a;
      }
      __syncthreads();
      {
        // ctx/nctx half: d = hf2*128 + dl
        int dl = tid & 127, eg = tid >> 7;
        const float* encb = enc + (size_t)cb*ENCx*Dx + hf2*128;
        float ca = 0.f, na = 0.f;
        #pragma unroll 4
        for (int i = 0; i < 128; ++i){
          int e = eg*128 + i;
          float av = albl[e];
          float nv = albl[(e + 511) & 511];
          float ev = encb[(size_t)e*256 + dl];
          ca = fmaf(av, ev, ca);
          na = fmaf(nv, ev, na);
        }
        cpn[0][eg][dl] = ca;
        cpn[1][eg][dl] = na;
      }
      __syncthreads();
      if (tid < 256){
        int z = tid >> 7, dd = tid & 127;
        float s = cpn[z][0][dd] + cpn[z][1][dd] + cpn[z][2][dd] + cpn[z][3][dd];
        x2p[z*128 + dd] = s;               // stage for bf16 pack
        if (z == 0)
          out[(size_t)cb*((size_t)DECx*Dx) + (size_t)t*Dx + hf2*128 + dd] = s;
      }
      __syncthreads();
      if (tid < 128){
        int z = tid >> 6, j = tid & 63;
        unsigned w = pack_bf16(x2p[z*128 + 2*j], x2p[z*128 + 2*j + 1]);
        st_rlx_u32(ctx32u + par*4096 + z*2048 + cb*128 + hf2*64 + j, w);
      }
      __syncthreads();                     // drain: ctx at coherence point
      if (tid == 0) st_rlx(cslot + cid, t + 1);
    }
  }
}

extern "C" void kernel_launch(void* const* d_in, const int* in_sizes, int n_in,
                              void* d_out, int out_size, void* d_ws, size_t ws_size,
                              hipStream_t stream)
{
  const float* enc    = (const float*)d_in[0];
  const float* mel    = (const float*)d_in[1];
  const int*   outlen = (const int*)d_in[3];
  const int*   cond   = (const int*)d_in[4];
  const float* Wih    = (const float*)d_in[5];
  const float* Whh    = (const float*)d_in[6];
  const float* bih    = (const float*)d_in[7];
  const float* bhh    = (const float*)d_in[8];
  const float* W1     = (const float*)d_in[9];
  const float* b1v    = (const float*)d_in[10];
  const float* W2     = (const float*)d_in[11];
  const float* Wlin   = (const float*)d_in[12];
  const float* blin   = (const float*)d_in[13];
  float* outp = (float*)d_out;
  float* wsf  = (float*)d_ws;

  (void)hipFuncSetAttribute((const void*)gmm_main,
                            hipFuncAttributeMaxDynamicSharedMemorySize,
                            (int)SMEM_BYTES);

  hipLaunchKernelGGL(gmm_init, dim3(16), dim3(64), 0, stream, wsf);

  void* args[] = {
    (void*)&enc, (void*)&mel, (void*)&outlen, (void*)&cond,
    (void*)&Wih, (void*)&Whh, (void*)&bih, (void*)&bhh,
    (void*)&W1, (void*)&b1v, (void*)&W2, (void*)&Wlin, (void*)&blin,
    (void*)&outp, (void*)&wsf
  };
  (void)hipLaunchCooperativeKernel((void*)gmm_main, dim3(NBLK), dim3(NTHR),
                                   args, SMEM_BYTES, stream);
}